// Round 16
// baseline (898.528 us; speedup 1.0000x reference)
//
#include <hip/hip_runtime.h>
#include <hip/hip_bf16.h>

#define NN 131072
#define EE 1048576
#define IN_F 74
#define HH 128
#define LL 3

using f32x4  = __attribute__((ext_vector_type(4))) float;
using f32x16 = __attribute__((ext_vector_type(16))) float;
using bf16x8 = __attribute__((ext_vector_type(8))) short;
typedef unsigned short ushort_t;
typedef unsigned int uint_t;

__device__ __forceinline__ short f2bf(float f) {
    __hip_bfloat16 b = __float2bfloat16(f);
    return __builtin_bit_cast(short, b);
}
__device__ __forceinline__ float bf2f(short s) {
    unsigned int u = ((unsigned int)(unsigned short)s) << 16;
    return __builtin_bit_cast(float, u);
}
__device__ __forceinline__ float bitf(uint_t u) { return __builtin_bit_cast(float, u); }
__device__ __forceinline__ float sigmoidf_(float x) { return 1.f / (1.f + __expf(-x)); }
__device__ __forceinline__ float tanhf_(float x)
{
    x = fminf(fmaxf(x, -15.f), 15.f);
    float e2 = __expf(2.f * x);
    return (e2 - 1.f) / (e2 + 1.f);
}

// ============ init: h = nf @ W_init -> bf16 hi/lo planes ============
__global__ __launch_bounds__(256) void k_init_gemm(
    const float* __restrict__ nf, const float* __restrict__ Wi,
    ushort_t* __restrict__ hhi, ushort_t* __restrict__ hlo)
{
    __shared__ float Wis[IN_F * HH];
    __shared__ float nfs[32 * IN_F];
    int b = blockIdx.x;
    int t = threadIdx.x;

    for (int i = t; i < IN_F * HH / 4; i += 256)
        reinterpret_cast<float4*>(Wis)[i] = reinterpret_cast<const float4*>(Wi)[i];
    {
        const float4* nf4 = reinterpret_cast<const float4*>(nf + (long)b * 32 * IN_F);
        for (int i = t; i < 32 * IN_F / 4; i += 256)
            reinterpret_cast<float4*>(nfs)[i] = nf4[i];
    }
    __syncthreads();

    int nl = t >> 3;
    int c0 = (t & 7) * 4;
    float acc[4][4];
#pragma unroll
    for (int hf = 0; hf < 4; ++hf)
#pragma unroll
        for (int j = 0; j < 4; ++j) acc[hf][j] = 0.f;

    const float* nrow = nfs + nl * IN_F;
#pragma unroll 2
    for (int k = 0; k < IN_F; ++k) {
        float a = nrow[k];
#pragma unroll
        for (int hf = 0; hf < 4; ++hf) {
            float4 wv = *reinterpret_cast<const float4*>(Wis + k * HH + hf * 32 + c0);
            acc[hf][0] += a * wv.x;
            acc[hf][1] += a * wv.y;
            acc[hf][2] += a * wv.z;
            acc[hf][3] += a * wv.w;
        }
    }

    int node = b * 32 + nl;
#pragma unroll
    for (int hf = 0; hf < 4; ++hf) {
        uint_t uh[2], ul[2];
#pragma unroll
        for (int p = 0; p < 2; ++p) {
            float v0 = acc[hf][p * 2], v1 = acc[hf][p * 2 + 1];
            short h0 = f2bf(v0), h1 = f2bf(v1);
            short l0 = f2bf(v0 - bf2f(h0)), l1 = f2bf(v1 - bf2f(h1));
            uh[p] = (uint_t)(ushort_t)h0 | ((uint_t)(ushort_t)h1 << 16);
            ul[p] = (uint_t)(ushort_t)l0 | ((uint_t)(ushort_t)l1 << 16);
        }
        long adr = (long)node * HH + hf * 32 + c0;
        *reinterpret_cast<uint2*>(hhi + adr) = make_uint2(uh[0], uh[1]);
        *reinterpret_cast<uint2*>(hlo + adr) = make_uint2(ul[0], ul[1]);
    }
}

// ============ CSR build ============
__global__ __launch_bounds__(256) void k_hist(const int* __restrict__ dsti, int* __restrict__ deg)
{
    int e = blockIdx.x * 256 + threadIdx.x;
    atomicAdd(&deg[dsti[e]], 1);
}

__global__ __launch_bounds__(256) void k_scan1(const int* __restrict__ deg, int* __restrict__ bsum)
{
    __shared__ int s[256];
    int b = blockIdx.x, t = threadIdx.x;
    int v = 0;
#pragma unroll
    for (int i = 0; i < 4; ++i) v += deg[b * 1024 + t * 4 + i];
    s[t] = v;
    __syncthreads();
    for (int st = 128; st > 0; st >>= 1) {
        if (t < st) s[t] += s[t + st];
        __syncthreads();
    }
    if (t == 0) bsum[b] = s[0];
}

__global__ void k_scan2(int* __restrict__ bsum, int nb)
{
    if (threadIdx.x == 0) {
        int run = 0;
        for (int i = 0; i < nb; ++i) { int v = bsum[i]; bsum[i] = run; run += v; }
    }
}

__global__ __launch_bounds__(256) void k_scan3(
    const int* __restrict__ deg, const int* __restrict__ bsum, int* __restrict__ row_start)
{
    __shared__ int s[256];
    int b = blockIdx.x, t = threadIdx.x;
    int base = b * 1024 + t * 4;
    int d0 = deg[base], d1 = deg[base + 1], d2 = deg[base + 2], d3 = deg[base + 3];
    int local = d0 + d1 + d2 + d3;
    s[t] = local;
    __syncthreads();
    for (int st = 1; st < 256; st <<= 1) {
        int v = (t >= st) ? s[t - st] : 0;
        __syncthreads();
        s[t] += v;
        __syncthreads();
    }
    int excl = s[t] - local + bsum[b];
    row_start[base] = excl;
    row_start[base + 1] = excl + d0;
    row_start[base + 2] = excl + d0 + d1;
    row_start[base + 3] = excl + d0 + d1 + d2;
    if (b == gridDim.x - 1 && t == 255) row_start[NN] = excl + local;
}

__global__ __launch_bounds__(256) void k_fill(
    const int* __restrict__ src, const int* __restrict__ dsti,
    const int* __restrict__ row_start, int* __restrict__ cursor, int* __restrict__ csr_src)
{
    int e = blockIdx.x * 256 + threadIdx.x;
    int d = dsti[e];
    int pos = atomicAdd(&cursor[d], 1);
    csr_src[row_start[d] + pos] = src[e];
}

// ============ weight split f32 -> (hi, lo) bf16 planes ============
__global__ __launch_bounds__(256) void k_split(
    const float* __restrict__ srcw, ushort_t* __restrict__ hi,
    ushort_t* __restrict__ lo, int n)
{
    int i = blockIdx.x * 256 + threadIdx.x;
    if (i >= n) return;
    float a = srcw[i];
    short h = f2bf(a);
    float rem = a - bf2f(h);
    hi[i] = (ushort_t)h;
    lo[i] = (ushort_t)f2bf(rem);
}

// ============ fused gather + x-GEMM: bf16-only gather (round-15 verified) ============
#define EIDX_CAP 1024

template <bool LDSIDX>
__device__ __forceinline__ void gather_node(
    const ushort_t* __restrict__ hhi, const int* __restrict__ eidx,
    const int* __restrict__ csr_src, int estart, int e0, int e1, int c4, int esel,
    float& a0, float& a1, float& a2, float& a3)
{
    int e = e0;
    for (; e + 7 < e1; e += 8) {
        uint2 v[4];
#pragma unroll
        for (int u = 0; u < 4; ++u) {
            int ee = e + u * 2 + esel;
            int s = LDSIDX ? eidx[ee] : csr_src[estart + ee];
            v[u] = *reinterpret_cast<const uint2*>(hhi + (long)s * HH + c4);
        }
#pragma unroll
        for (int u = 0; u < 4; ++u) {
            a0 += bitf(v[u].x << 16);
            a1 += bitf(v[u].x & 0xffff0000u);
            a2 += bitf(v[u].y << 16);
            a3 += bitf(v[u].y & 0xffff0000u);
        }
    }
    for (; e + 1 < e1; e += 2) {
        int ee = e + esel;
        int s = LDSIDX ? eidx[ee] : csr_src[estart + ee];
        uint2 vv = *reinterpret_cast<const uint2*>(hhi + (long)s * HH + c4);
        a0 += bitf(vv.x << 16);
        a1 += bitf(vv.x & 0xffff0000u);
        a2 += bitf(vv.y << 16);
        a3 += bitf(vv.y & 0xffff0000u);
    }
    if (e < e1 && esel == 0) {
        int s = LDSIDX ? eidx[e] : csr_src[estart + e];
        uint2 vv = *reinterpret_cast<const uint2*>(hhi + (long)s * HH + c4);
        a0 += bitf(vv.x << 16);
        a1 += bitf(vv.x & 0xffff0000u);
        a2 += bitf(vv.y << 16);
        a3 += bitf(vv.y & 0xffff0000u);
    }
}

__global__ __launch_bounds__(256) void k_x(
    const ushort_t* __restrict__ hhi, const ushort_t* __restrict__ hlo,
    const int* __restrict__ row_start, const int* __restrict__ csr_src,
    const ushort_t* __restrict__ lWhi, const ushort_t* __restrict__ lWlo,
    const float* __restrict__ lb,
    ushort_t* __restrict__ xhi, ushort_t* __restrict__ xlo)
{
    __shared__ float aggs[32 * 128];
    __shared__ int eidx[EIDX_CAP];
    char* abase = (char*)aggs;
    int n0 = blockIdx.x * 32;
    int t = threadIdx.x;
    int w = t >> 6, lane = t & 63;

    int estart = row_start[n0];
    int ecount = row_start[n0 + 32] - estart;
    bool inl = (ecount <= EIDX_CAP);
    for (int i = t; i < ecount && i < EIDX_CAP; i += 256)
        eidx[i] = csr_src[estart + i];
    __syncthreads();

    int c4 = (lane & 31) * 4;
    int esel = lane >> 5;

    for (int i = 0; i < 8; ++i) {
        int nl = w * 8 + i;
        int node = n0 + nl;
        int e0 = row_start[node] - estart;
        int e1 = row_start[node + 1] - estart;
        float a0 = 0.f, a1 = 0.f, a2 = 0.f, a3 = 0.f;
        if (inl)
            gather_node<true>(hhi, eidx, csr_src, estart, e0, e1, c4, esel, a0, a1, a2, a3);
        else
            gather_node<false>(hhi, eidx, csr_src, estart, e0, e1, c4, esel, a0, a1, a2, a3);
        a0 += __shfl_xor(a0, 32, 64);
        a1 += __shfl_xor(a1, 32, 64);
        a2 += __shfl_xor(a2, 32, 64);
        a3 += __shfl_xor(a3, 32, 64);
        if (lane < 32) {
            int swz = (nl & 7) << 4;
            float4 st = make_float4(a0, a1, a2, a3);
            *reinterpret_cast<float4*>(abase + ((nl * 512 + c4 * 4) ^ swz)) = st;
        }
    }
    __syncthreads();

    int ng = w >> 1, jg = w & 1;
    int l16 = lane & 15, lq = lane >> 4;

    f32x4 acc[4];
#pragma unroll
    for (int js = 0; js < 4; ++js) acc[js] = (f32x4){0.f, 0.f, 0.f, 0.f};

#pragma unroll
    for (int kk = 0; kk < 4; ++kk) {
        int k0 = kk * 32;
        int nodeL = ng * 16 + l16;
        int kb = (k0 + lq * 8) * 4;
        int swz = (nodeL & 7) << 4;
        float4 f0 = *reinterpret_cast<const float4*>(abase + ((nodeL * 512 + kb) ^ swz));
        float4 f1 = *reinterpret_cast<const float4*>(abase + ((nodeL * 512 + kb + 16) ^ swz));
        float av[8] = {f0.x, f0.y, f0.z, f0.w, f1.x, f1.y, f1.z, f1.w};
        bf16x8 ahi, alo;
#pragma unroll
        for (int e = 0; e < 8; ++e) {
            short hh_ = f2bf(av[e]);
            ahi[e] = hh_;
            alo[e] = f2bf(av[e] - bf2f(hh_));
        }
#pragma unroll
        for (int js = 0; js < 4; ++js) {
            int jrow = jg * 64 + js * 16 + l16;
            bf16x8 Bh = *reinterpret_cast<const bf16x8*>(lWhi + (long)jrow * HH + k0 + lq * 8);
            bf16x8 Bl = *reinterpret_cast<const bf16x8*>(lWlo + (long)jrow * HH + k0 + lq * 8);
            acc[js] = __builtin_amdgcn_mfma_f32_16x16x32_bf16(ahi, Bh, acc[js], 0, 0, 0);
            acc[js] = __builtin_amdgcn_mfma_f32_16x16x32_bf16(ahi, Bl, acc[js], 0, 0, 0);
            acc[js] = __builtin_amdgcn_mfma_f32_16x16x32_bf16(alo, Bh, acc[js], 0, 0, 0);
        }
    }

#pragma unroll
    for (int js = 0; js < 4; ++js) {
        int j = jg * 64 + js * 16 + l16;
        float bj = lb[j];
#pragma unroll
        for (int r = 0; r < 4; ++r) {
            int node = n0 + ng * 16 + lq * 4 + r;
            float v = fmaxf(acc[js][r] + bj, 0.f);
            long adr = (long)node * HH + j;
            short hi_ = f2bf(v);
            xhi[adr] = (ushort_t)hi_;
            xlo[adr] = (ushort_t)f2bf(v - bf2f(hi_));
        }
    }
}

// ============ fused GRU v5-async: T14 reg-prefetch of next B slab ============
// Same structure/barriers as v5; loads for slab s+1 issued right after slab s's
// ds_writes so L2 latency hides under stage-s compute. Named pf0..pf7 (rule #20).
#define LDSA(p) ((p) * 16384)
#define LDSB(p) (65536 + (p) * 32768)

__device__ __forceinline__ void stage_slab(
    const ushort_t* __restrict__ g, char* lds, int tid, int nchunk512)
{
    const uint4* g4 = reinterpret_cast<const uint4*>(g);
#pragma unroll
    for (int i = 0; i < 4; ++i) {
        if (i >= nchunk512) break;
        int c = i * 512 + tid;
        int L = c * 16;
        int row = L >> 8, kb = L & 255;
        *reinterpret_cast<uint4*>(lds + row * 256 + (kb ^ ((row & 15) << 4))) = g4[c];
    }
}

__device__ __forceinline__ void gru_half(
    f32x16& acc, const char* smem, int pAhi, int myoff, int rs_my,
    int jjoff, int rs_jj, int lh)
{
    bf16x8 Ahi[8], Alo[8];
#pragma unroll
    for (int kc = 0; kc < 8; ++kc) {
        int kb = kc * 32 + lh * 16;
        Ahi[kc] = *reinterpret_cast<const bf16x8*>(smem + LDSA(pAhi)     + myoff + (kb ^ rs_my));
        Alo[kc] = *reinterpret_cast<const bf16x8*>(smem + LDSA(pAhi + 1) + myoff + (kb ^ rs_my));
    }
#pragma unroll
    for (int kc = 0; kc < 8; ++kc) {
        int kb = kc * 32 + lh * 16;
        bf16x8 wh = *reinterpret_cast<const bf16x8*>(smem + LDSB(0) + jjoff + (kb ^ rs_jj));
        bf16x8 wl = *reinterpret_cast<const bf16x8*>(smem + LDSB(1) + jjoff + (kb ^ rs_jj));
        acc = __builtin_amdgcn_mfma_f32_32x32x16_bf16(Ahi[kc], wh, acc, 0, 0, 0);
        acc = __builtin_amdgcn_mfma_f32_32x32x16_bf16(Ahi[kc], wl, acc, 0, 0, 0);
        acc = __builtin_amdgcn_mfma_f32_32x32x16_bf16(Alo[kc], wh, acc, 0, 0, 0);
    }
}

// load next slab-pair into named regs (no LDS touch; stays in flight over compute)
#define LOAD_PF(SH, SL)                                                   \
    do {                                                                  \
        const uint4* gh_ = reinterpret_cast<const uint4*>(SH);            \
        const uint4* gl_ = reinterpret_cast<const uint4*>(SL);            \
        pf0 = gh_[t]; pf1 = gh_[512 + t]; pf2 = gh_[1024 + t]; pf3 = gh_[1536 + t]; \
        pf4 = gl_[t]; pf5 = gl_[512 + t]; pf6 = gl_[1024 + t]; pf7 = gl_[1536 + t]; \
    } while (0)

#define WRB(BASE, I, V)                                                   \
    do {                                                                  \
        int c_ = (I) * 512 + t;                                           \
        int L_ = c_ * 16;                                                 \
        int row_ = L_ >> 8, kb_ = L_ & 255;                               \
        *reinterpret_cast<uint4*>(smem + (BASE) + row_ * 256 + (kb_ ^ ((row_ & 15) << 4))) = (V); \
    } while (0)

#define WRITE_PF()                                                        \
    do {                                                                  \
        WRB(LDSB(0), 0, pf0); WRB(LDSB(0), 1, pf1);                       \
        WRB(LDSB(0), 2, pf2); WRB(LDSB(0), 3, pf3);                       \
        WRB(LDSB(1), 0, pf4); WRB(LDSB(1), 1, pf5);                       \
        WRB(LDSB(1), 2, pf6); WRB(LDSB(1), 3, pf7);                       \
    } while (0)

__global__ __launch_bounds__(512, 2) void k_gru(
    const ushort_t* __restrict__ xhi, const ushort_t* __restrict__ xlo,
    ushort_t* __restrict__ hhi, ushort_t* __restrict__ hlo,
    const ushort_t* __restrict__ Wihhi, const ushort_t* __restrict__ Wihlo,
    const ushort_t* __restrict__ Whhhi, const ushort_t* __restrict__ Whhlo,
    const float* __restrict__ bi, const float* __restrict__ bh)
{
    __shared__ uint4 smem4[131072 / 16];
    char* smem = (char*)smem4;

    int t = threadIdx.x;
    int w = t >> 6, lane = t & 63;
    int ng = w >> 2, og = w & 3;
    int l31 = lane & 31, lh = lane >> 5;
    int n0 = blockIdx.x * 64;
    int myrow = ng * 32 + l31;
    int jj = og * 32 + l31;
    int myoff = myrow * 256, rs_my = (myrow & 15) << 4;
    int jjoff = jj * 256,   rs_jj = (jj & 15) << 4;

    uint4 pf0, pf1, pf2, pf3, pf4, pf5, pf6, pf7;

    // ---- prologue: B0 loads in flight while A planes stage ----
    LOAD_PF(Whhhi + 256 * HH, Whhlo + 256 * HH);
    stage_slab(xhi + (long)n0 * HH, smem + LDSA(0), t, 2);
    stage_slab(xlo + (long)n0 * HH, smem + LDSA(1), t, 2);
    stage_slab(hhi + (long)n0 * HH, smem + LDSA(2), t, 2);
    stage_slab(hlo + (long)n0 * HH, smem + LDSA(3), t, 2);
    WRITE_PF();                           // B0 (Whh_n)
    LOAD_PF(Wihhi, Wihlo);                // B1 in flight
    __syncthreads();

    f32x16 acc1;
#pragma unroll
    for (int i = 0; i < 16; ++i) acc1[i] = 0.f;
    gru_half(acc1, smem, 2, myoff, rs_my, jjoff, rs_jj, lh);   // stage 0: h @ Whh_n

    f32x16 acc2;
#pragma unroll
    for (int i = 0; i < 16; ++i) acc2[i] = 0.f;
    __syncthreads();
    WRITE_PF();                           // B1 (Wih_r)
    LOAD_PF(Whhhi, Whhlo);                // B2 in flight
    __syncthreads();
    gru_half(acc2, smem, 0, myoff, rs_my, jjoff, rs_jj, lh);   // stage 1: x @ Wih_r

    __syncthreads();
    WRITE_PF();                           // B2 (Whh_r)
    LOAD_PF(Wihhi + 256 * HH, Wihlo + 256 * HH);               // B3 in flight
    __syncthreads();
    gru_half(acc2, smem, 2, myoff, rs_my, jjoff, rs_jj, lh);   // stage 2: h @ Whh_r
    {
        float bR = bi[jj] + bh[jj];
        float bNh = bh[256 + jj];
#pragma unroll
        for (int i = 0; i < 16; ++i)
            acc1[i] = sigmoidf_(acc2[i] + bR) * (acc1[i] + bNh);
    }

#pragma unroll
    for (int i = 0; i < 16; ++i) acc2[i] = 0.f;
    __syncthreads();
    WRITE_PF();                           // B3 (Wih_n)
    LOAD_PF(Wihhi + 128 * HH, Wihlo + 128 * HH);               // B4 in flight
    __syncthreads();
    gru_half(acc2, smem, 0, myoff, rs_my, jjoff, rs_jj, lh);   // stage 3: x @ Wih_n
    {
        float bNi = bi[256 + jj];
#pragma unroll
        for (int i = 0; i < 16; ++i)
            acc1[i] = tanhf_(acc2[i] + bNi + acc1[i]);
    }

#pragma unroll
    for (int i = 0; i < 16; ++i) acc2[i] = 0.f;
    __syncthreads();
    WRITE_PF();                           // B4 (Wih_z)
    LOAD_PF(Whhhi + 128 * HH, Whhlo + 128 * HH);               // B5 in flight
    __syncthreads();
    gru_half(acc2, smem, 0, myoff, rs_my, jjoff, rs_jj, lh);   // stage 4: x @ Wih_z

    __syncthreads();
    WRITE_PF();                           // B5 (Whh_z)
    __syncthreads();
    gru_half(acc2, smem, 2, myoff, rs_my, jjoff, rs_jj, lh);   // stage 5: h @ Whh_z

    // ---- epilogue ----
    {
        float bZ = bi[128 + jj] + bh[128 + jj];
        int kb2 = 2 * jj;
#pragma unroll
        for (int reg = 0; reg < 16; ++reg) {
            int ndl = ng * 32 + (reg & 3) + 8 * (reg >> 2) + 4 * lh;
            long adr = (long)(n0 + ndl) * HH + jj;
            int rsn = (ndl & 15) << 4;
            float hold = bf2f(*reinterpret_cast<const short*>(smem + LDSA(2) + ndl * 256 + (kb2 ^ rsn)))
                       + bf2f(*reinterpret_cast<const short*>(smem + LDSA(3) + ndl * 256 + (kb2 ^ rsn)));
            float zv = sigmoidf_(acc2[reg] + bZ);
            float hp = (1.f - zv) * acc1[reg] + zv * hold;
            short hi_ = f2bf(hp);
            hhi[adr] = (ushort_t)hi_;
            hlo[adr] = (ushort_t)f2bf(hp - bf2f(hi_));
        }
    }
}

// ============ final: d_out = hhi + hlo (f32) ============
__global__ __launch_bounds__(256) void k_copy(
    const uint_t* __restrict__ hhi, const uint_t* __restrict__ hlo,
    float2* __restrict__ out)
{
    long i = (long)blockIdx.x * 256 + threadIdx.x;
    uint_t vh = hhi[i], vl = hlo[i];
    float2 o;
    o.x = bitf(vh << 16) + bitf(vl << 16);
    o.y = bitf(vh & 0xffff0000u) + bitf(vl & 0xffff0000u);
    out[i] = o;
}

extern "C" void kernel_launch(void* const* d_in, const int* in_sizes, int n_in,
                              void* d_out, int out_size, void* d_ws, size_t ws_size,
                              hipStream_t stream)
{
    const float* nf     = (const float*)d_in[0];
    const int*   src    = (const int*)d_in[1];
    const int*   dsti   = (const int*)d_in[2];
    const float* W_init = (const float*)d_in[3];
    const float* lin_W  = (const float*)d_in[4];
    const float* lin_b  = (const float*)d_in[5];
    const float* Wih    = (const float*)d_in[6];
    const float* Whh    = (const float*)d_in[7];
    const float* bih    = (const float*)d_in[8];
    const float* bhh    = (const float*)d_in[9];

    char* ws = (char*)d_ws;
    ushort_t* hhi = (ushort_t*)ws;
    ushort_t* hlo = (ushort_t*)(ws + (32ull << 20));
    ushort_t* xhi = (ushort_t*)(ws + (64ull << 20));
    ushort_t* xlo = (ushort_t*)(ws + (96ull << 20));
    int* deg    = (int*)(ws + (64ull << 20));
    int* cursor = (int*)(ws + (64ull << 20) + (1 << 20));
    int* bsum   = (int*)(ws + (64ull << 20) + (2 << 20));

    char* ob = (char*)d_out;
    int* row_start = (int*)ob;
    int* csr_src   = (int*)(ob + (1ull << 20));
    ushort_t* lWhi  = (ushort_t*)(ob + (6ull << 20));
    ushort_t* lWlo  = lWhi  + 3 * 128 * 128;
    ushort_t* Wihhi = lWlo  + 3 * 128 * 128;
    ushort_t* Wihlo = Wihhi + 3 * 384 * 128;
    ushort_t* Whhhi = Wihlo + 3 * 384 * 128;
    ushort_t* Whhlo = Whhhi + 3 * 384 * 128;

    k_init_gemm<<<NN / 32, 256, 0, stream>>>(nf, W_init, hhi, hlo);

    hipMemsetAsync(deg, 0, (size_t)NN * 4, stream);
    hipMemsetAsync(cursor, 0, (size_t)NN * 4, stream);
    k_hist<<<EE / 256, 256, 0, stream>>>(dsti, deg);
    k_scan1<<<NN / 1024, 256, 0, stream>>>(deg, bsum);
    k_scan2<<<1, 64, 0, stream>>>(bsum, NN / 1024);
    k_scan3<<<NN / 1024, 256, 0, stream>>>(deg, bsum, row_start);
    k_fill<<<EE / 256, 256, 0, stream>>>(src, dsti, row_start, cursor, csr_src);

    k_split<<<(3 * 128 * 128 + 255) / 256, 256, 0, stream>>>(lin_W, lWhi, lWlo, 3 * 128 * 128);
    k_split<<<(3 * 384 * 128 + 255) / 256, 256, 0, stream>>>(Wih, Wihhi, Wihlo, 3 * 384 * 128);
    k_split<<<(3 * 384 * 128 + 255) / 256, 256, 0, stream>>>(Whh, Whhhi, Whhlo, 3 * 384 * 128);

    for (int l = 0; l < LL; ++l) {
        k_x<<<NN / 32, 256, 0, stream>>>(
            hhi, hlo, row_start, csr_src,
            lWhi + (long)l * 128 * 128, lWlo + (long)l * 128 * 128,
            lin_b + (long)l * 128, xhi, xlo);
        k_gru<<<NN / 64, 512, 0, stream>>>(
            xhi, xlo, hhi, hlo,
            Wihhi + (long)l * 384 * 128, Wihlo + (long)l * 384 * 128,
            Whhhi + (long)l * 384 * 128, Whhlo + (long)l * 384 * 128,
            bih + (long)l * 384, bhh + (long)l * 384);
    }

    k_copy<<<NN * HH / 2 / 256, 256, 0, stream>>>((const uint_t*)hhi, (const uint_t*)hlo, (float2*)d_out);
}

// Round 17
// 828.288 us; speedup vs baseline: 1.0848x; 1.0848x over previous
//
#include <hip/hip_runtime.h>
#include <hip/hip_bf16.h>

#define NN 131072
#define EE 1048576
#define IN_F 74
#define HH 128
#define LL 3

using f32x4  = __attribute__((ext_vector_type(4))) float;
using f32x16 = __attribute__((ext_vector_type(16))) float;
using bf16x8 = __attribute__((ext_vector_type(8))) short;
typedef unsigned short ushort_t;
typedef unsigned int uint_t;

__device__ __forceinline__ short f2bf(float f) {
    __hip_bfloat16 b = __float2bfloat16(f);
    return __builtin_bit_cast(short, b);
}
__device__ __forceinline__ float bf2f(short s) {
    unsigned int u = ((unsigned int)(unsigned short)s) << 16;
    return __builtin_bit_cast(float, u);
}
__device__ __forceinline__ float bitf(uint_t u) { return __builtin_bit_cast(float, u); }
__device__ __forceinline__ float sigmoidf_(float x) { return 1.f / (1.f + __expf(-x)); }
__device__ __forceinline__ float tanhf_(float x)
{
    x = fminf(fmaxf(x, -15.f), 15.f);
    float e2 = __expf(2.f * x);
    return (e2 - 1.f) / (e2 + 1.f);
}

// ============ init: h = nf @ W_init -> bf16 hi/lo planes ============
__global__ __launch_bounds__(256) void k_init_gemm(
    const float* __restrict__ nf, const float* __restrict__ Wi,
    ushort_t* __restrict__ hhi, ushort_t* __restrict__ hlo)
{
    __shared__ float Wis[IN_F * HH];
    __shared__ float nfs[32 * IN_F];
    int b = blockIdx.x;
    int t = threadIdx.x;

    for (int i = t; i < IN_F * HH / 4; i += 256)
        reinterpret_cast<float4*>(Wis)[i] = reinterpret_cast<const float4*>(Wi)[i];
    {
        const float4* nf4 = reinterpret_cast<const float4*>(nf + (long)b * 32 * IN_F);
        for (int i = t; i < 32 * IN_F / 4; i += 256)
            reinterpret_cast<float4*>(nfs)[i] = nf4[i];
    }
    __syncthreads();

    int nl = t >> 3;
    int c0 = (t & 7) * 4;
    float acc[4][4];
#pragma unroll
    for (int hf = 0; hf < 4; ++hf)
#pragma unroll
        for (int j = 0; j < 4; ++j) acc[hf][j] = 0.f;

    const float* nrow = nfs + nl * IN_F;
#pragma unroll 2
    for (int k = 0; k < IN_F; ++k) {
        float a = nrow[k];
#pragma unroll
        for (int hf = 0; hf < 4; ++hf) {
            float4 wv = *reinterpret_cast<const float4*>(Wis + k * HH + hf * 32 + c0);
            acc[hf][0] += a * wv.x;
            acc[hf][1] += a * wv.y;
            acc[hf][2] += a * wv.z;
            acc[hf][3] += a * wv.w;
        }
    }

    int node = b * 32 + nl;
#pragma unroll
    for (int hf = 0; hf < 4; ++hf) {
        uint_t uh[2], ul[2];
#pragma unroll
        for (int p = 0; p < 2; ++p) {
            float v0 = acc[hf][p * 2], v1 = acc[hf][p * 2 + 1];
            short h0 = f2bf(v0), h1 = f2bf(v1);
            short l0 = f2bf(v0 - bf2f(h0)), l1 = f2bf(v1 - bf2f(h1));
            uh[p] = (uint_t)(ushort_t)h0 | ((uint_t)(ushort_t)h1 << 16);
            ul[p] = (uint_t)(ushort_t)l0 | ((uint_t)(ushort_t)l1 << 16);
        }
        long adr = (long)node * HH + hf * 32 + c0;
        *reinterpret_cast<uint2*>(hhi + adr) = make_uint2(uh[0], uh[1]);
        *reinterpret_cast<uint2*>(hlo + adr) = make_uint2(ul[0], ul[1]);
    }
}

// ============ CSR build ============
__global__ __launch_bounds__(256) void k_hist(const int* __restrict__ dsti, int* __restrict__ deg)
{
    int e = blockIdx.x * 256 + threadIdx.x;
    atomicAdd(&deg[dsti[e]], 1);
}

__global__ __launch_bounds__(256) void k_scan1(const int* __restrict__ deg, int* __restrict__ bsum)
{
    __shared__ int s[256];
    int b = blockIdx.x, t = threadIdx.x;
    int v = 0;
#pragma unroll
    for (int i = 0; i < 4; ++i) v += deg[b * 1024 + t * 4 + i];
    s[t] = v;
    __syncthreads();
    for (int st = 128; st > 0; st >>= 1) {
        if (t < st) s[t] += s[t + st];
        __syncthreads();
    }
    if (t == 0) bsum[b] = s[0];
}

__global__ void k_scan2(int* __restrict__ bsum, int nb)
{
    if (threadIdx.x == 0) {
        int run = 0;
        for (int i = 0; i < nb; ++i) { int v = bsum[i]; bsum[i] = run; run += v; }
    }
}

__global__ __launch_bounds__(256) void k_scan3(
    const int* __restrict__ deg, const int* __restrict__ bsum, int* __restrict__ row_start)
{
    __shared__ int s[256];
    int b = blockIdx.x, t = threadIdx.x;
    int base = b * 1024 + t * 4;
    int d0 = deg[base], d1 = deg[base + 1], d2 = deg[base + 2], d3 = deg[base + 3];
    int local = d0 + d1 + d2 + d3;
    s[t] = local;
    __syncthreads();
    for (int st = 1; st < 256; st <<= 1) {
        int v = (t >= st) ? s[t - st] : 0;
        __syncthreads();
        s[t] += v;
        __syncthreads();
    }
    int excl = s[t] - local + bsum[b];
    row_start[base] = excl;
    row_start[base + 1] = excl + d0;
    row_start[base + 2] = excl + d0 + d1;
    row_start[base + 3] = excl + d0 + d1 + d2;
    if (b == gridDim.x - 1 && t == 255) row_start[NN] = excl + local;
}

__global__ __launch_bounds__(256) void k_fill(
    const int* __restrict__ src, const int* __restrict__ dsti,
    const int* __restrict__ row_start, int* __restrict__ cursor, int* __restrict__ csr_src)
{
    int e = blockIdx.x * 256 + threadIdx.x;
    int d = dsti[e];
    int pos = atomicAdd(&cursor[d], 1);
    csr_src[row_start[d] + pos] = src[e];
}

// ============ weight split f32 -> (hi, lo) bf16 planes ============
__global__ __launch_bounds__(256) void k_split(
    const float* __restrict__ srcw, ushort_t* __restrict__ hi,
    ushort_t* __restrict__ lo, int n)
{
    int i = blockIdx.x * 256 + threadIdx.x;
    if (i >= n) return;
    float a = srcw[i];
    short h = f2bf(a);
    float rem = a - bf2f(h);
    hi[i] = (ushort_t)h;
    lo[i] = (ushort_t)f2bf(rem);
}

// ============ fused gather + x-GEMM: bf16-only gather (round-15 verified) ============
#define EIDX_CAP 1024

template <bool LDSIDX>
__device__ __forceinline__ void gather_node(
    const ushort_t* __restrict__ hhi, const int* __restrict__ eidx,
    const int* __restrict__ csr_src, int estart, int e0, int e1, int c4, int esel,
    float& a0, float& a1, float& a2, float& a3)
{
    int e = e0;
    for (; e + 7 < e1; e += 8) {
        uint2 v[4];
#pragma unroll
        for (int u = 0; u < 4; ++u) {
            int ee = e + u * 2 + esel;
            int s = LDSIDX ? eidx[ee] : csr_src[estart + ee];
            v[u] = *reinterpret_cast<const uint2*>(hhi + (long)s * HH + c4);
        }
#pragma unroll
        for (int u = 0; u < 4; ++u) {
            a0 += bitf(v[u].x << 16);
            a1 += bitf(v[u].x & 0xffff0000u);
            a2 += bitf(v[u].y << 16);
            a3 += bitf(v[u].y & 0xffff0000u);
        }
    }
    for (; e + 1 < e1; e += 2) {
        int ee = e + esel;
        int s = LDSIDX ? eidx[ee] : csr_src[estart + ee];
        uint2 vv = *reinterpret_cast<const uint2*>(hhi + (long)s * HH + c4);
        a0 += bitf(vv.x << 16);
        a1 += bitf(vv.x & 0xffff0000u);
        a2 += bitf(vv.y << 16);
        a3 += bitf(vv.y & 0xffff0000u);
    }
    if (e < e1 && esel == 0) {
        int s = LDSIDX ? eidx[e] : csr_src[estart + e];
        uint2 vv = *reinterpret_cast<const uint2*>(hhi + (long)s * HH + c4);
        a0 += bitf(vv.x << 16);
        a1 += bitf(vv.x & 0xffff0000u);
        a2 += bitf(vv.y << 16);
        a3 += bitf(vv.y & 0xffff0000u);
    }
}

__global__ __launch_bounds__(256) void k_x(
    const ushort_t* __restrict__ hhi, const ushort_t* __restrict__ hlo,
    const int* __restrict__ row_start, const int* __restrict__ csr_src,
    const ushort_t* __restrict__ lWhi, const ushort_t* __restrict__ lWlo,
    const float* __restrict__ lb,
    ushort_t* __restrict__ xhi, ushort_t* __restrict__ xlo)
{
    __shared__ float aggs[32 * 128];
    __shared__ int eidx[EIDX_CAP];
    char* abase = (char*)aggs;
    int n0 = blockIdx.x * 32;
    int t = threadIdx.x;
    int w = t >> 6, lane = t & 63;

    int estart = row_start[n0];
    int ecount = row_start[n0 + 32] - estart;
    bool inl = (ecount <= EIDX_CAP);
    for (int i = t; i < ecount && i < EIDX_CAP; i += 256)
        eidx[i] = csr_src[estart + i];
    __syncthreads();

    int c4 = (lane & 31) * 4;
    int esel = lane >> 5;

    for (int i = 0; i < 8; ++i) {
        int nl = w * 8 + i;
        int node = n0 + nl;
        int e0 = row_start[node] - estart;
        int e1 = row_start[node + 1] - estart;
        float a0 = 0.f, a1 = 0.f, a2 = 0.f, a3 = 0.f;
        if (inl)
            gather_node<true>(hhi, eidx, csr_src, estart, e0, e1, c4, esel, a0, a1, a2, a3);
        else
            gather_node<false>(hhi, eidx, csr_src, estart, e0, e1, c4, esel, a0, a1, a2, a3);
        a0 += __shfl_xor(a0, 32, 64);
        a1 += __shfl_xor(a1, 32, 64);
        a2 += __shfl_xor(a2, 32, 64);
        a3 += __shfl_xor(a3, 32, 64);
        if (lane < 32) {
            int swz = (nl & 7) << 4;
            float4 st = make_float4(a0, a1, a2, a3);
            *reinterpret_cast<float4*>(abase + ((nl * 512 + c4 * 4) ^ swz)) = st;
        }
    }
    __syncthreads();

    int ng = w >> 1, jg = w & 1;
    int l16 = lane & 15, lq = lane >> 4;

    f32x4 acc[4];
#pragma unroll
    for (int js = 0; js < 4; ++js) acc[js] = (f32x4){0.f, 0.f, 0.f, 0.f};

#pragma unroll
    for (int kk = 0; kk < 4; ++kk) {
        int k0 = kk * 32;
        int nodeL = ng * 16 + l16;
        int kb = (k0 + lq * 8) * 4;
        int swz = (nodeL & 7) << 4;
        float4 f0 = *reinterpret_cast<const float4*>(abase + ((nodeL * 512 + kb) ^ swz));
        float4 f1 = *reinterpret_cast<const float4*>(abase + ((nodeL * 512 + kb + 16) ^ swz));
        float av[8] = {f0.x, f0.y, f0.z, f0.w, f1.x, f1.y, f1.z, f1.w};
        bf16x8 ahi, alo;
#pragma unroll
        for (int e = 0; e < 8; ++e) {
            short hh_ = f2bf(av[e]);
            ahi[e] = hh_;
            alo[e] = f2bf(av[e] - bf2f(hh_));
        }
#pragma unroll
        for (int js = 0; js < 4; ++js) {
            int jrow = jg * 64 + js * 16 + l16;
            bf16x8 Bh = *reinterpret_cast<const bf16x8*>(lWhi + (long)jrow * HH + k0 + lq * 8);
            bf16x8 Bl = *reinterpret_cast<const bf16x8*>(lWlo + (long)jrow * HH + k0 + lq * 8);
            acc[js] = __builtin_amdgcn_mfma_f32_16x16x32_bf16(ahi, Bh, acc[js], 0, 0, 0);
            acc[js] = __builtin_amdgcn_mfma_f32_16x16x32_bf16(ahi, Bl, acc[js], 0, 0, 0);
            acc[js] = __builtin_amdgcn_mfma_f32_16x16x32_bf16(alo, Bh, acc[js], 0, 0, 0);
        }
    }

#pragma unroll
    for (int js = 0; js < 4; ++js) {
        int j = jg * 64 + js * 16 + l16;
        float bj = lb[j];
#pragma unroll
        for (int r = 0; r < 4; ++r) {
            int node = n0 + ng * 16 + lq * 4 + r;
            float v = fmaxf(acc[js][r] + bj, 0.f);
            long adr = (long)node * HH + j;
            short hi_ = f2bf(v);
            xhi[adr] = (ushort_t)hi_;
            xlo[adr] = (ushort_t)f2bf(v - bf2f(hi_));
        }
    }
}

// ============ fused GRU v10: bf16-hi weights, 2 gates/stage, 3 stages, 5 barriers ============
// Block: 64 nodes, 512 threads (8 waves: ng=w>>2, og=w&3). Wave: 32 nodes x 32 j.
// A (x,h) keeps hi+lo split in LDS; B = hi-only gate slabs, two per stage.
#define LDSA(p) ((p) * 16384)
#define LDSB(p) (65536 + (p) * 32768)

__device__ __forceinline__ void stage_slab(
    const ushort_t* __restrict__ g, char* lds, int tid, int nchunk512)
{
    const uint4* g4 = reinterpret_cast<const uint4*>(g);
#pragma unroll
    for (int i = 0; i < 4; ++i) {
        if (i >= nchunk512) break;
        int c = i * 512 + tid;
        int L = c * 16;
        int row = L >> 8, kb = L & 255;
        *reinterpret_cast<uint4*>(lds + row * 256 + (kb ^ ((row & 15) << 4))) = g4[c];
    }
}

// acc += A(pAhi: hi+lo planes) @ B(one hi slab at bbase); 2 MFMAs/chunk
__device__ __forceinline__ void gru_half2(
    f32x16& acc, const char* smem, int pAhi, int bbase,
    int myoff, int rs_my, int jjoff, int rs_jj, int lh)
{
#pragma unroll
    for (int kc = 0; kc < 8; ++kc) {
        int kb = kc * 32 + lh * 16;
        bf16x8 ah = *reinterpret_cast<const bf16x8*>(smem + LDSA(pAhi)     + myoff + (kb ^ rs_my));
        bf16x8 al = *reinterpret_cast<const bf16x8*>(smem + LDSA(pAhi + 1) + myoff + (kb ^ rs_my));
        bf16x8 wh = *reinterpret_cast<const bf16x8*>(smem + bbase + jjoff + (kb ^ rs_jj));
        acc = __builtin_amdgcn_mfma_f32_32x32x16_bf16(ah, wh, acc, 0, 0, 0);
        acc = __builtin_amdgcn_mfma_f32_32x32x16_bf16(al, wh, acc, 0, 0, 0);
    }
}

__global__ __launch_bounds__(512, 2) void k_gru(
    const ushort_t* __restrict__ xhi, const ushort_t* __restrict__ xlo,
    ushort_t* __restrict__ hhi, ushort_t* __restrict__ hlo,
    const ushort_t* __restrict__ Wihhi, const ushort_t* __restrict__ Whhhi,
    const float* __restrict__ bi, const float* __restrict__ bh)
{
    __shared__ uint4 smem4[131072 / 16];
    char* smem = (char*)smem4;

    int t = threadIdx.x;
    int w = t >> 6, lane = t & 63;
    int ng = w >> 2, og = w & 3;
    int l31 = lane & 31, lh = lane >> 5;
    int n0 = blockIdx.x * 64;
    int myrow = ng * 32 + l31;
    int jj = og * 32 + l31;
    int myoff = myrow * 256, rs_my = (myrow & 15) << 4;
    int jjoff = jj * 256,   rs_jj = (jj & 15) << 4;

    // ---- P1 stage: A planes + {Whh_n, Whh_r} ----
    stage_slab(xhi + (long)n0 * HH, smem + LDSA(0), t, 2);
    stage_slab(xlo + (long)n0 * HH, smem + LDSA(1), t, 2);
    stage_slab(hhi + (long)n0 * HH, smem + LDSA(2), t, 2);
    stage_slab(hlo + (long)n0 * HH, smem + LDSA(3), t, 2);
    stage_slab(Whhhi + 256 * HH, smem + LDSB(0), t, 4);   // Whh_n
    stage_slab(Whhhi,            smem + LDSB(1), t, 4);   // Whh_r
    __syncthreads();

    f32x16 accNH, accR;
#pragma unroll
    for (int i = 0; i < 16; ++i) { accNH[i] = 0.f; accR[i] = 0.f; }
    gru_half2(accNH, smem, 2, LDSB(0), myoff, rs_my, jjoff, rs_jj, lh);  // h@Whh_n
    gru_half2(accR,  smem, 2, LDSB(1), myoff, rs_my, jjoff, rs_jj, lh);  // h@Whh_r

    // ---- P2 stage: {Wih_r, Wih_n} ----
    __syncthreads();
    stage_slab(Wihhi,            smem + LDSB(0), t, 4);   // Wih_r
    stage_slab(Wihhi + 256 * HH, smem + LDSB(1), t, 4);   // Wih_n
    __syncthreads();
    gru_half2(accR, smem, 0, LDSB(0), myoff, rs_my, jjoff, rs_jj, lh);   // += x@Wih_r
    f32x16 accNI;
#pragma unroll
    for (int i = 0; i < 16; ++i) accNI[i] = 0.f;
    gru_half2(accNI, smem, 0, LDSB(1), myoff, rs_my, jjoff, rs_jj, lh);  // x@Wih_n
    // folds: r then n (result in accNH as "n")
    {
        float bR = bi[jj] + bh[jj];
        float bNh = bh[256 + jj];
        float bNi = bi[256 + jj];
#pragma unroll
        for (int i = 0; i < 16; ++i) {
            float rn = sigmoidf_(accR[i] + bR) * (accNH[i] + bNh);
            accNH[i] = tanhf_(accNI[i] + bNi + rn);
        }
    }

    // ---- P3 stage: {Wih_z, Whh_z} ----
    __syncthreads();
    stage_slab(Wihhi + 128 * HH, smem + LDSB(0), t, 4);   // Wih_z
    stage_slab(Whhhi + 128 * HH, smem + LDSB(1), t, 4);   // Whh_z
    __syncthreads();
#pragma unroll
    for (int i = 0; i < 16; ++i) accR[i] = 0.f;           // reuse accR as accZ
    gru_half2(accR, smem, 0, LDSB(0), myoff, rs_my, jjoff, rs_jj, lh);   // x@Wih_z
    gru_half2(accR, smem, 2, LDSB(1), myoff, rs_my, jjoff, rs_jj, lh);   // h@Whh_z

    // ---- epilogue: z = sigmoid(accZ + bZ); h' = (1-z)*n + z*h_old (hold from LDS) ----
    {
        float bZ = bi[128 + jj] + bh[128 + jj];
        int kb2 = 2 * jj;
#pragma unroll
        for (int reg = 0; reg < 16; ++reg) {
            int ndl = ng * 32 + (reg & 3) + 8 * (reg >> 2) + 4 * lh;
            long adr = (long)(n0 + ndl) * HH + jj;
            int rsn = (ndl & 15) << 4;
            float hold = bf2f(*reinterpret_cast<const short*>(smem + LDSA(2) + ndl * 256 + (kb2 ^ rsn)))
                       + bf2f(*reinterpret_cast<const short*>(smem + LDSA(3) + ndl * 256 + (kb2 ^ rsn)));
            float zv = sigmoidf_(accR[reg] + bZ);
            float hp = (1.f - zv) * accNH[reg] + zv * hold;
            short hi_ = f2bf(hp);
            hhi[adr] = (ushort_t)hi_;
            hlo[adr] = (ushort_t)f2bf(hp - bf2f(hi_));
        }
    }
}

// ============ final: d_out = hhi + hlo (f32) ============
__global__ __launch_bounds__(256) void k_copy(
    const uint_t* __restrict__ hhi, const uint_t* __restrict__ hlo,
    float2* __restrict__ out)
{
    long i = (long)blockIdx.x * 256 + threadIdx.x;
    uint_t vh = hhi[i], vl = hlo[i];
    float2 o;
    o.x = bitf(vh << 16) + bitf(vl << 16);
    o.y = bitf(vh & 0xffff0000u) + bitf(vl & 0xffff0000u);
    out[i] = o;
}

extern "C" void kernel_launch(void* const* d_in, const int* in_sizes, int n_in,
                              void* d_out, int out_size, void* d_ws, size_t ws_size,
                              hipStream_t stream)
{
    const float* nf     = (const float*)d_in[0];
    const int*   src    = (const int*)d_in[1];
    const int*   dsti   = (const int*)d_in[2];
    const float* W_init = (const float*)d_in[3];
    const float* lin_W  = (const float*)d_in[4];
    const float* lin_b  = (const float*)d_in[5];
    const float* Wih    = (const float*)d_in[6];
    const float* Whh    = (const float*)d_in[7];
    const float* bih    = (const float*)d_in[8];
    const float* bhh    = (const float*)d_in[9];

    char* ws = (char*)d_ws;
    ushort_t* hhi = (ushort_t*)ws;
    ushort_t* hlo = (ushort_t*)(ws + (32ull << 20));
    ushort_t* xhi = (ushort_t*)(ws + (64ull << 20));
    ushort_t* xlo = (ushort_t*)(ws + (96ull << 20));
    int* deg    = (int*)(ws + (64ull << 20));
    int* cursor = (int*)(ws + (64ull << 20) + (1 << 20));
    int* bsum   = (int*)(ws + (64ull << 20) + (2 << 20));

    char* ob = (char*)d_out;
    int* row_start = (int*)ob;
    int* csr_src   = (int*)(ob + (1ull << 20));
    ushort_t* lWhi  = (ushort_t*)(ob + (6ull << 20));
    ushort_t* lWlo  = lWhi  + 3 * 128 * 128;
    ushort_t* Wihhi = lWlo  + 3 * 128 * 128;
    ushort_t* Wihlo = Wihhi + 3 * 384 * 128;
    ushort_t* Whhhi = Wihlo + 3 * 384 * 128;
    ushort_t* Whhlo = Whhhi + 3 * 384 * 128;

    k_init_gemm<<<NN / 32, 256, 0, stream>>>(nf, W_init, hhi, hlo);

    hipMemsetAsync(deg, 0, (size_t)NN * 4, stream);
    hipMemsetAsync(cursor, 0, (size_t)NN * 4, stream);
    k_hist<<<EE / 256, 256, 0, stream>>>(dsti, deg);
    k_scan1<<<NN / 1024, 256, 0, stream>>>(deg, bsum);
    k_scan2<<<1, 64, 0, stream>>>(bsum, NN / 1024);
    k_scan3<<<NN / 1024, 256, 0, stream>>>(deg, bsum, row_start);
    k_fill<<<EE / 256, 256, 0, stream>>>(src, dsti, row_start, cursor, csr_src);

    k_split<<<(3 * 128 * 128 + 255) / 256, 256, 0, stream>>>(lin_W, lWhi, lWlo, 3 * 128 * 128);
    k_split<<<(3 * 384 * 128 + 255) / 256, 256, 0, stream>>>(Wih, Wihhi, Wihlo, 3 * 384 * 128);
    k_split<<<(3 * 384 * 128 + 255) / 256, 256, 0, stream>>>(Whh, Whhhi, Whhlo, 3 * 384 * 128);

    for (int l = 0; l < LL; ++l) {
        k_x<<<NN / 32, 256, 0, stream>>>(
            hhi, hlo, row_start, csr_src,
            lWhi + (long)l * 128 * 128, lWlo + (long)l * 128 * 128,
            lin_b + (long)l * 128, xhi, xlo);
        k_gru<<<NN / 64, 512, 0, stream>>>(
            xhi, xlo, hhi, hlo,
            Wihhi + (long)l * 384 * 128, Whhhi + (long)l * 384 * 128,
            bih + (long)l * 384, bhh + (long)l * 384);
    }

    k_copy<<<NN * HH / 2 / 256, 256, 0, stream>>>((const uint_t*)hhi, (const uint_t*)hlo, (float2*)d_out);
}

// Round 18
// 818.729 us; speedup vs baseline: 1.0975x; 1.0117x over previous
//
#include <hip/hip_runtime.h>
#include <hip/hip_bf16.h>

#define NN 131072
#define EE 1048576
#define IN_F 74
#define HH 128
#define LL 3

using f32x4  = __attribute__((ext_vector_type(4))) float;
using f32x16 = __attribute__((ext_vector_type(16))) float;
using bf16x8 = __attribute__((ext_vector_type(8))) short;
typedef unsigned short ushort_t;
typedef unsigned int uint_t;

__device__ __forceinline__ short f2bf(float f) {
    __hip_bfloat16 b = __float2bfloat16(f);
    return __builtin_bit_cast(short, b);
}
__device__ __forceinline__ float bf2f(short s) {
    unsigned int u = ((unsigned int)(unsigned short)s) << 16;
    return __builtin_bit_cast(float, u);
}
__device__ __forceinline__ float bitf(uint_t u) { return __builtin_bit_cast(float, u); }
__device__ __forceinline__ float sigmoidf_(float x) { return 1.f / (1.f + __expf(-x)); }
__device__ __forceinline__ float tanhf_(float x)
{
    x = fminf(fmaxf(x, -15.f), 15.f);
    float e2 = __expf(2.f * x);
    return (e2 - 1.f) / (e2 + 1.f);
}

// ============ init: h = nf @ W_init -> bf16 hi/lo planes ============
__global__ __launch_bounds__(256) void k_init_gemm(
    const float* __restrict__ nf, const float* __restrict__ Wi,
    ushort_t* __restrict__ hhi, ushort_t* __restrict__ hlo)
{
    __shared__ float Wis[IN_F * HH];
    __shared__ float nfs[32 * IN_F];
    int b = blockIdx.x;
    int t = threadIdx.x;

    for (int i = t; i < IN_F * HH / 4; i += 256)
        reinterpret_cast<float4*>(Wis)[i] = reinterpret_cast<const float4*>(Wi)[i];
    {
        const float4* nf4 = reinterpret_cast<const float4*>(nf + (long)b * 32 * IN_F);
        for (int i = t; i < 32 * IN_F / 4; i += 256)
            reinterpret_cast<float4*>(nfs)[i] = nf4[i];
    }
    __syncthreads();

    int nl = t >> 3;
    int c0 = (t & 7) * 4;
    float acc[4][4];
#pragma unroll
    for (int hf = 0; hf < 4; ++hf)
#pragma unroll
        for (int j = 0; j < 4; ++j) acc[hf][j] = 0.f;

    const float* nrow = nfs + nl * IN_F;
#pragma unroll 2
    for (int k = 0; k < IN_F; ++k) {
        float a = nrow[k];
#pragma unroll
        for (int hf = 0; hf < 4; ++hf) {
            float4 wv = *reinterpret_cast<const float4*>(Wis + k * HH + hf * 32 + c0);
            acc[hf][0] += a * wv.x;
            acc[hf][1] += a * wv.y;
            acc[hf][2] += a * wv.z;
            acc[hf][3] += a * wv.w;
        }
    }

    int node = b * 32 + nl;
#pragma unroll
    for (int hf = 0; hf < 4; ++hf) {
        uint_t uh[2], ul[2];
#pragma unroll
        for (int p = 0; p < 2; ++p) {
            float v0 = acc[hf][p * 2], v1 = acc[hf][p * 2 + 1];
            short h0 = f2bf(v0), h1 = f2bf(v1);
            short l0 = f2bf(v0 - bf2f(h0)), l1 = f2bf(v1 - bf2f(h1));
            uh[p] = (uint_t)(ushort_t)h0 | ((uint_t)(ushort_t)h1 << 16);
            ul[p] = (uint_t)(ushort_t)l0 | ((uint_t)(ushort_t)l1 << 16);
        }
        long adr = (long)node * HH + hf * 32 + c0;
        *reinterpret_cast<uint2*>(hhi + adr) = make_uint2(uh[0], uh[1]);
        *reinterpret_cast<uint2*>(hlo + adr) = make_uint2(ul[0], ul[1]);
    }
}

// ============ CSR build ============
__global__ __launch_bounds__(256) void k_hist(const int* __restrict__ dsti, int* __restrict__ deg)
{
    int e = blockIdx.x * 256 + threadIdx.x;
    atomicAdd(&deg[dsti[e]], 1);
}

__global__ __launch_bounds__(256) void k_scan1(const int* __restrict__ deg, int* __restrict__ bsum)
{
    __shared__ int s[256];
    int b = blockIdx.x, t = threadIdx.x;
    int v = 0;
#pragma unroll
    for (int i = 0; i < 4; ++i) v += deg[b * 1024 + t * 4 + i];
    s[t] = v;
    __syncthreads();
    for (int st = 128; st > 0; st >>= 1) {
        if (t < st) s[t] += s[t + st];
        __syncthreads();
    }
    if (t == 0) bsum[b] = s[0];
}

__global__ void k_scan2(int* __restrict__ bsum, int nb)
{
    if (threadIdx.x == 0) {
        int run = 0;
        for (int i = 0; i < nb; ++i) { int v = bsum[i]; bsum[i] = run; run += v; }
    }
}

__global__ __launch_bounds__(256) void k_scan3(
    const int* __restrict__ deg, const int* __restrict__ bsum, int* __restrict__ row_start)
{
    __shared__ int s[256];
    int b = blockIdx.x, t = threadIdx.x;
    int base = b * 1024 + t * 4;
    int d0 = deg[base], d1 = deg[base + 1], d2 = deg[base + 2], d3 = deg[base + 3];
    int local = d0 + d1 + d2 + d3;
    s[t] = local;
    __syncthreads();
    for (int st = 1; st < 256; st <<= 1) {
        int v = (t >= st) ? s[t - st] : 0;
        __syncthreads();
        s[t] += v;
        __syncthreads();
    }
    int excl = s[t] - local + bsum[b];
    row_start[base] = excl;
    row_start[base + 1] = excl + d0;
    row_start[base + 2] = excl + d0 + d1;
    row_start[base + 3] = excl + d0 + d1 + d2;
    if (b == gridDim.x - 1 && t == 255) row_start[NN] = excl + local;
}

__global__ __launch_bounds__(256) void k_fill(
    const int* __restrict__ src, const int* __restrict__ dsti,
    const int* __restrict__ row_start, int* __restrict__ cursor, int* __restrict__ csr_src)
{
    int e = blockIdx.x * 256 + threadIdx.x;
    int d = dsti[e];
    int pos = atomicAdd(&cursor[d], 1);
    csr_src[row_start[d] + pos] = src[e];
}

// ============ weight split f32 -> (hi, lo) bf16 planes ============
__global__ __launch_bounds__(256) void k_split(
    const float* __restrict__ srcw, ushort_t* __restrict__ hi,
    ushort_t* __restrict__ lo, int n)
{
    int i = blockIdx.x * 256 + threadIdx.x;
    if (i >= n) return;
    float a = srcw[i];
    short h = f2bf(a);
    float rem = a - bf2f(h);
    hi[i] = (ushort_t)h;
    lo[i] = (ushort_t)f2bf(rem);
}

// ============ fused gather + x-GEMM: bf16-only gather (round-15 verified) ============
#define EIDX_CAP 1024

template <bool LDSIDX>
__device__ __forceinline__ void gather_node(
    const ushort_t* __restrict__ hhi, const int* __restrict__ eidx,
    const int* __restrict__ csr_src, int estart, int e0, int e1, int c4, int esel,
    float& a0, float& a1, float& a2, float& a3)
{
    int e = e0;
    for (; e + 7 < e1; e += 8) {
        uint2 v[4];
#pragma unroll
        for (int u = 0; u < 4; ++u) {
            int ee = e + u * 2 + esel;
            int s = LDSIDX ? eidx[ee] : csr_src[estart + ee];
            v[u] = *reinterpret_cast<const uint2*>(hhi + (long)s * HH + c4);
        }
#pragma unroll
        for (int u = 0; u < 4; ++u) {
            a0 += bitf(v[u].x << 16);
            a1 += bitf(v[u].x & 0xffff0000u);
            a2 += bitf(v[u].y << 16);
            a3 += bitf(v[u].y & 0xffff0000u);
        }
    }
    for (; e + 1 < e1; e += 2) {
        int ee = e + esel;
        int s = LDSIDX ? eidx[ee] : csr_src[estart + ee];
        uint2 vv = *reinterpret_cast<const uint2*>(hhi + (long)s * HH + c4);
        a0 += bitf(vv.x << 16);
        a1 += bitf(vv.x & 0xffff0000u);
        a2 += bitf(vv.y << 16);
        a3 += bitf(vv.y & 0xffff0000u);
    }
    if (e < e1 && esel == 0) {
        int s = LDSIDX ? eidx[e] : csr_src[estart + e];
        uint2 vv = *reinterpret_cast<const uint2*>(hhi + (long)s * HH + c4);
        a0 += bitf(vv.x << 16);
        a1 += bitf(vv.x & 0xffff0000u);
        a2 += bitf(vv.y << 16);
        a3 += bitf(vv.y & 0xffff0000u);
    }
}

__global__ __launch_bounds__(256) void k_x(
    const ushort_t* __restrict__ hhi, const ushort_t* __restrict__ hlo,
    const int* __restrict__ row_start, const int* __restrict__ csr_src,
    const ushort_t* __restrict__ lWhi, const ushort_t* __restrict__ lWlo,
    const float* __restrict__ lb,
    ushort_t* __restrict__ xhi, ushort_t* __restrict__ xlo)
{
    __shared__ float aggs[32 * 128];
    __shared__ int eidx[EIDX_CAP];
    char* abase = (char*)aggs;
    int n0 = blockIdx.x * 32;
    int t = threadIdx.x;
    int w = t >> 6, lane = t & 63;

    int estart = row_start[n0];
    int ecount = row_start[n0 + 32] - estart;
    bool inl = (ecount <= EIDX_CAP);
    for (int i = t; i < ecount && i < EIDX_CAP; i += 256)
        eidx[i] = csr_src[estart + i];
    __syncthreads();

    int c4 = (lane & 31) * 4;
    int esel = lane >> 5;

    for (int i = 0; i < 8; ++i) {
        int nl = w * 8 + i;
        int node = n0 + nl;
        int e0 = row_start[node] - estart;
        int e1 = row_start[node + 1] - estart;
        float a0 = 0.f, a1 = 0.f, a2 = 0.f, a3 = 0.f;
        if (inl)
            gather_node<true>(hhi, eidx, csr_src, estart, e0, e1, c4, esel, a0, a1, a2, a3);
        else
            gather_node<false>(hhi, eidx, csr_src, estart, e0, e1, c4, esel, a0, a1, a2, a3);
        a0 += __shfl_xor(a0, 32, 64);
        a1 += __shfl_xor(a1, 32, 64);
        a2 += __shfl_xor(a2, 32, 64);
        a3 += __shfl_xor(a3, 32, 64);
        if (lane < 32) {
            int swz = (nl & 7) << 4;
            float4 st = make_float4(a0, a1, a2, a3);
            *reinterpret_cast<float4*>(abase + ((nl * 512 + c4 * 4) ^ swz)) = st;
        }
    }
    __syncthreads();

    int ng = w >> 1, jg = w & 1;
    int l16 = lane & 15, lq = lane >> 4;

    f32x4 acc[4];
#pragma unroll
    for (int js = 0; js < 4; ++js) acc[js] = (f32x4){0.f, 0.f, 0.f, 0.f};

#pragma unroll
    for (int kk = 0; kk < 4; ++kk) {
        int k0 = kk * 32;
        int nodeL = ng * 16 + l16;
        int kb = (k0 + lq * 8) * 4;
        int swz = (nodeL & 7) << 4;
        float4 f0 = *reinterpret_cast<const float4*>(abase + ((nodeL * 512 + kb) ^ swz));
        float4 f1 = *reinterpret_cast<const float4*>(abase + ((nodeL * 512 + kb + 16) ^ swz));
        float av[8] = {f0.x, f0.y, f0.z, f0.w, f1.x, f1.y, f1.z, f1.w};
        bf16x8 ahi, alo;
#pragma unroll
        for (int e = 0; e < 8; ++e) {
            short hh_ = f2bf(av[e]);
            ahi[e] = hh_;
            alo[e] = f2bf(av[e] - bf2f(hh_));
        }
#pragma unroll
        for (int js = 0; js < 4; ++js) {
            int jrow = jg * 64 + js * 16 + l16;
            bf16x8 Bh = *reinterpret_cast<const bf16x8*>(lWhi + (long)jrow * HH + k0 + lq * 8);
            bf16x8 Bl = *reinterpret_cast<const bf16x8*>(lWlo + (long)jrow * HH + k0 + lq * 8);
            acc[js] = __builtin_amdgcn_mfma_f32_16x16x32_bf16(ahi, Bh, acc[js], 0, 0, 0);
            acc[js] = __builtin_amdgcn_mfma_f32_16x16x32_bf16(ahi, Bl, acc[js], 0, 0, 0);
            acc[js] = __builtin_amdgcn_mfma_f32_16x16x32_bf16(alo, Bh, acc[js], 0, 0, 0);
        }
    }

#pragma unroll
    for (int js = 0; js < 4; ++js) {
        int j = jg * 64 + js * 16 + l16;
        float bj = lb[j];
#pragma unroll
        for (int r = 0; r < 4; ++r) {
            int node = n0 + ng * 16 + lq * 4 + r;
            float v = fmaxf(acc[js][r] + bj, 0.f);
            long adr = (long)node * HH + j;
            short hi_ = f2bf(v);
            xhi[adr] = (ushort_t)hi_;
            xlo[adr] = (ushort_t)f2bf(v - bf2f(hi_));
        }
    }
}

// ============ fused GRU v11: bf16-hi weights, 3 gates/stage, 2 stages, 3 barriers ============
// Block: 64 nodes, 512 threads (8 waves: ng=w>>2, og=w&3). Wave: 32 nodes x 32 j.
// LDS 160 KB: A (x,h hi/lo) 64 KB + three 32 KB B slabs (AITER precedent for 160 KB blocks).
#define LDSA(p) ((p) * 16384)
#define LDSB3(p) (65536 + (p) * 32768)

__device__ __forceinline__ void stage_slab(
    const ushort_t* __restrict__ g, char* lds, int tid, int nchunk512)
{
    const uint4* g4 = reinterpret_cast<const uint4*>(g);
#pragma unroll
    for (int i = 0; i < 4; ++i) {
        if (i >= nchunk512) break;
        int c = i * 512 + tid;
        int L = c * 16;
        int row = L >> 8, kb = L & 255;
        *reinterpret_cast<uint4*>(lds + row * 256 + (kb ^ ((row & 15) << 4))) = g4[c];
    }
}

// acc += A(pAhi: hi+lo planes) @ B(one hi slab at bbase); 2 MFMAs/chunk
__device__ __forceinline__ void gru_half2(
    f32x16& acc, const char* smem, int pAhi, int bbase,
    int myoff, int rs_my, int jjoff, int rs_jj, int lh)
{
#pragma unroll
    for (int kc = 0; kc < 8; ++kc) {
        int kb = kc * 32 + lh * 16;
        bf16x8 ah = *reinterpret_cast<const bf16x8*>(smem + LDSA(pAhi)     + myoff + (kb ^ rs_my));
        bf16x8 al = *reinterpret_cast<const bf16x8*>(smem + LDSA(pAhi + 1) + myoff + (kb ^ rs_my));
        bf16x8 wh = *reinterpret_cast<const bf16x8*>(smem + bbase + jjoff + (kb ^ rs_jj));
        acc = __builtin_amdgcn_mfma_f32_32x32x16_bf16(ah, wh, acc, 0, 0, 0);
        acc = __builtin_amdgcn_mfma_f32_32x32x16_bf16(al, wh, acc, 0, 0, 0);
    }
}

__global__ __launch_bounds__(512, 2) void k_gru(
    const ushort_t* __restrict__ xhi, const ushort_t* __restrict__ xlo,
    ushort_t* __restrict__ hhi, ushort_t* __restrict__ hlo,
    const ushort_t* __restrict__ Wihhi, const ushort_t* __restrict__ Whhhi,
    const float* __restrict__ bi, const float* __restrict__ bh)
{
    __shared__ uint4 smem4[163840 / 16];   // 160 KB
    char* smem = (char*)smem4;

    int t = threadIdx.x;
    int w = t >> 6, lane = t & 63;
    int ng = w >> 2, og = w & 3;
    int l31 = lane & 31, lh = lane >> 5;
    int n0 = blockIdx.x * 64;
    int myrow = ng * 32 + l31;
    int jj = og * 32 + l31;
    int myoff = myrow * 256, rs_my = (myrow & 15) << 4;
    int jjoff = jj * 256,   rs_jj = (jj & 15) << 4;

    // ---- P1 stage: A planes + {Whh_n, Whh_r, Wih_r} ----
    stage_slab(xhi + (long)n0 * HH, smem + LDSA(0), t, 2);
    stage_slab(xlo + (long)n0 * HH, smem + LDSA(1), t, 2);
    stage_slab(hhi + (long)n0 * HH, smem + LDSA(2), t, 2);
    stage_slab(hlo + (long)n0 * HH, smem + LDSA(3), t, 2);
    stage_slab(Whhhi + 256 * HH, smem + LDSB3(0), t, 4);   // Whh_n
    stage_slab(Whhhi,            smem + LDSB3(1), t, 4);   // Whh_r
    stage_slab(Wihhi,            smem + LDSB3(2), t, 4);   // Wih_r
    __syncthreads();

    f32x16 accNH, accR;
#pragma unroll
    for (int i = 0; i < 16; ++i) { accNH[i] = 0.f; accR[i] = 0.f; }
    gru_half2(accNH, smem, 2, LDSB3(0), myoff, rs_my, jjoff, rs_jj, lh);  // h@Whh_n
    gru_half2(accR,  smem, 2, LDSB3(1), myoff, rs_my, jjoff, rs_jj, lh);  // h@Whh_r
    gru_half2(accR,  smem, 0, LDSB3(2), myoff, rs_my, jjoff, rs_jj, lh);  // += x@Wih_r
    // fold r: accNH := sigmoid(accR + bR) * (accNH + bNh)   (= rn term)
    {
        float bR = bi[jj] + bh[jj];
        float bNh = bh[256 + jj];
#pragma unroll
        for (int i = 0; i < 16; ++i)
            accNH[i] = sigmoidf_(accR[i] + bR) * (accNH[i] + bNh);
    }

    // ---- P2 stage: {Wih_n, Wih_z, Whh_z} ----
    __syncthreads();
    stage_slab(Wihhi + 256 * HH, smem + LDSB3(0), t, 4);   // Wih_n
    stage_slab(Wihhi + 128 * HH, smem + LDSB3(1), t, 4);   // Wih_z
    stage_slab(Whhhi + 128 * HH, smem + LDSB3(2), t, 4);   // Whh_z
    __syncthreads();

    f32x16 accNI;
#pragma unroll
    for (int i = 0; i < 16; ++i) accNI[i] = 0.f;
    gru_half2(accNI, smem, 0, LDSB3(0), myoff, rs_my, jjoff, rs_jj, lh);  // x@Wih_n
    // fold n: accNH := tanh(accNI + bNi + rn)
    {
        float bNi = bi[256 + jj];
#pragma unroll
        for (int i = 0; i < 16; ++i)
            accNH[i] = tanhf_(accNI[i] + bNi + accNH[i]);
    }
#pragma unroll
    for (int i = 0; i < 16; ++i) accR[i] = 0.f;            // reuse accR as accZ
    gru_half2(accR, smem, 0, LDSB3(1), myoff, rs_my, jjoff, rs_jj, lh);   // x@Wih_z
    gru_half2(accR, smem, 2, LDSB3(2), myoff, rs_my, jjoff, rs_jj, lh);   // h@Whh_z

    // ---- epilogue: z = sigmoid(accZ + bZ); h' = (1-z)*n + z*h_old (hold from LDS) ----
    {
        float bZ = bi[128 + jj] + bh[128 + jj];
        int kb2 = 2 * jj;
#pragma unroll
        for (int reg = 0; reg < 16; ++reg) {
            int ndl = ng * 32 + (reg & 3) + 8 * (reg >> 2) + 4 * lh;
            long adr = (long)(n0 + ndl) * HH + jj;
            int rsn = (ndl & 15) << 4;
            float hold = bf2f(*reinterpret_cast<const short*>(smem + LDSA(2) + ndl * 256 + (kb2 ^ rsn)))
                       + bf2f(*reinterpret_cast<const short*>(smem + LDSA(3) + ndl * 256 + (kb2 ^ rsn)));
            float zv = sigmoidf_(accR[reg] + bZ);
            float hp = (1.f - zv) * accNH[reg] + zv * hold;
            short hi_ = f2bf(hp);
            hhi[adr] = (ushort_t)hi_;
            hlo[adr] = (ushort_t)f2bf(hp - bf2f(hi_));
        }
    }
}

// ============ final: d_out = hhi + hlo (f32) ============
__global__ __launch_bounds__(256) void k_copy(
    const uint_t* __restrict__ hhi, const uint_t* __restrict__ hlo,
    float2* __restrict__ out)
{
    long i = (long)blockIdx.x * 256 + threadIdx.x;
    uint_t vh = hhi[i], vl = hlo[i];
    float2 o;
    o.x = bitf(vh << 16) + bitf(vl << 16);
    o.y = bitf(vh & 0xffff0000u) + bitf(vl & 0xffff0000u);
    out[i] = o;
}

extern "C" void kernel_launch(void* const* d_in, const int* in_sizes, int n_in,
                              void* d_out, int out_size, void* d_ws, size_t ws_size,
                              hipStream_t stream)
{
    const float* nf     = (const float*)d_in[0];
    const int*   src    = (const int*)d_in[1];
    const int*   dsti   = (const int*)d_in[2];
    const float* W_init = (const float*)d_in[3];
    const float* lin_W  = (const float*)d_in[4];
    const float* lin_b  = (const float*)d_in[5];
    const float* Wih    = (const float*)d_in[6];
    const float* Whh    = (const float*)d_in[7];
    const float* bih    = (const float*)d_in[8];
    const float* bhh    = (const float*)d_in[9];

    char* ws = (char*)d_ws;
    ushort_t* hhi = (ushort_t*)ws;
    ushort_t* hlo = (ushort_t*)(ws + (32ull << 20));
    ushort_t* xhi = (ushort_t*)(ws + (64ull << 20));
    ushort_t* xlo = (ushort_t*)(ws + (96ull << 20));
    int* deg    = (int*)(ws + (64ull << 20));
    int* cursor = (int*)(ws + (64ull << 20) + (1 << 20));
    int* bsum   = (int*)(ws + (64ull << 20) + (2 << 20));

    char* ob = (char*)d_out;
    int* row_start = (int*)ob;
    int* csr_src   = (int*)(ob + (1ull << 20));
    ushort_t* lWhi  = (ushort_t*)(ob + (6ull << 20));
    ushort_t* lWlo  = lWhi  + 3 * 128 * 128;
    ushort_t* Wihhi = lWlo  + 3 * 128 * 128;
    ushort_t* Wihlo = Wihhi + 3 * 384 * 128;
    ushort_t* Whhhi = Wihlo + 3 * 384 * 128;
    ushort_t* Whhlo = Whhhi + 3 * 384 * 128;

    k_init_gemm<<<NN / 32, 256, 0, stream>>>(nf, W_init, hhi, hlo);

    hipMemsetAsync(deg, 0, (size_t)NN * 4, stream);
    hipMemsetAsync(cursor, 0, (size_t)NN * 4, stream);
    k_hist<<<EE / 256, 256, 0, stream>>>(dsti, deg);
    k_scan1<<<NN / 1024, 256, 0, stream>>>(deg, bsum);
    k_scan2<<<1, 64, 0, stream>>>(bsum, NN / 1024);
    k_scan3<<<NN / 1024, 256, 0, stream>>>(deg, bsum, row_start);
    k_fill<<<EE / 256, 256, 0, stream>>>(src, dsti, row_start, cursor, csr_src);

    k_split<<<(3 * 128 * 128 + 255) / 256, 256, 0, stream>>>(lin_W, lWhi, lWlo, 3 * 128 * 128);
    k_split<<<(3 * 384 * 128 + 255) / 256, 256, 0, stream>>>(Wih, Wihhi, Wihlo, 3 * 384 * 128);
    k_split<<<(3 * 384 * 128 + 255) / 256, 256, 0, stream>>>(Whh, Whhhi, Whhlo, 3 * 384 * 128);

    for (int l = 0; l < LL; ++l) {
        k_x<<<NN / 32, 256, 0, stream>>>(
            hhi, hlo, row_start, csr_src,
            lWhi + (long)l * 128 * 128, lWlo + (long)l * 128 * 128,
            lin_b + (long)l * 128, xhi, xlo);
        k_gru<<<NN / 64, 512, 0, stream>>>(
            xhi, xlo, hhi, hlo,
            Wihhi + (long)l * 384 * 128, Whhhi + (long)l * 384 * 128,
            bih + (long)l * 384, bhh + (long)l * 384);
    }

    k_copy<<<NN * HH / 2 / 256, 256, 0, stream>>>((const uint_t*)hhi, (const uint_t*)hlo, (float2*)d_out);
}